// Round 13
// baseline (129.748 us; speedup 1.0000x reference)
//
#include <hip/hip_runtime.h>
#include <math.h>

#define BB 2
#define TT 512
#define UU 48
#define DD 512
#define HH 1024
#define KK 128

typedef _Float16 f16x8 __attribute__((ext_vector_type(8)));
typedef __fp16 fp16x2_t __attribute__((ext_vector_type(2)));
typedef float floatx4 __attribute__((ext_vector_type(4)));

// tanh(x) = 1 - 2/(e^{2x}+1). Safe at +-inf (no clamp).
__device__ __forceinline__ f16x8 tanh8(f16x8 x) {
    f16x8 o;
#pragma unroll
    for (int i = 0; i < 8; i += 2) {
        float s0 = (float)x[i];
        float s1 = (float)x[i + 1];
        float e0 = __expf(s0 + s0);
        float e1 = __expf(s1 + s1);
        float r0 = __builtin_amdgcn_rcpf(e0 + 1.0f);
        float r1 = __builtin_amdgcn_rcpf(e1 + 1.0f);
        fp16x2_t p = __builtin_amdgcn_cvt_pkrtz(fmaf(-2.0f, r0, 1.0f),
                                                fmaf(-2.0f, r1, 1.0f));
        o[i] = (_Float16)p[0];
        o[i + 1] = (_Float16)p[1];
    }
    return o;
}

__device__ __forceinline__ f16x8 cvt8(float4 a, float4 b) {
    f16x8 v;
    v[0] = (_Float16)a.x; v[1] = (_Float16)a.y;
    v[2] = (_Float16)a.z; v[3] = (_Float16)a.w;
    v[4] = (_Float16)b.x; v[5] = (_Float16)b.y;
    v[6] = (_Float16)b.z; v[7] = (_Float16)b.w;
    return v;
}

// ---------------- mid: 184 blocks (<=256, one per CU -> balanced) ----------
// region 0 (bid<128):   imgHf = f16(img·Wi)      64-row x 128-col tiles
// region 1 (128..151):  labHf = f16(lab·Wl+b1)   32-row x 128-col tiles
// region 2 (152..167):  seg   = (img·cw+cb)*mask 64-row x 128-col tiles
// region 3 (168..183):  W2s swizzle fp32->f16
__global__ __launch_bounds__(256) void mid_kernel5(
    const float* __restrict__ img, const float* __restrict__ labf,
    const float* __restrict__ W1, const float* __restrict__ W2,
    const float* __restrict__ conv_w,
    const float* __restrict__ b1, const float* __restrict__ conv_b,
    const float* __restrict__ masks,
    _Float16* __restrict__ imgHf, _Float16* __restrict__ labHf,
    _Float16* __restrict__ W2s, float* __restrict__ seg_out) {
    int bid = blockIdx.x, tid = threadIdx.x;
    if (bid >= 168) {  // W2 swizzle: W2s[(h>>3)*1024 + k*8 + (h&7)] = W2[k][h]
        int base = (bid - 168) * 256 + tid;
#pragma unroll
        for (int i = 0; i < 32; ++i) {
            int o = base + i * 4096;
            int hg = o >> 10, kk2 = (o >> 3) & 127, hl = o & 7;
            W2s[o] = (_Float16)W2[(size_t)kk2 * HH + hg * 8 + hl];
        }
        return;
    }
    __shared__ __align__(16) _Float16 a_s[64][72];
    __shared__ __align__(16) _Float16 w_s[8192];
    int lane = tid & 63, wv = tid >> 6;
    int q = lane >> 4, r = lane & 15;
    int arow = tid >> 3, acol = (tid & 7) * 8;
    int wn = tid >> 3, wk = tid & 7;

    if (bid >= 128 && bid < 152) {
        // ---- region 1: labH, 32-row tile, waves split m(2) x n(2x64) ----
        int i = bid - 128;
        int r0 = (i % 3) * 32, n0b = (i / 3) * 128;
        int m0 = (wv & 1) * 16, n0w = (wv >> 1) * 64;
        const float* aptr = &labf[(size_t)(r0 + (arow & 31)) * DD + acol];
        floatx4 acc[4] = {};
        float4 pa0, pa1, pw[4][2];
        pa0 = *(const float4*)aptr;
        pa1 = *(const float4*)(aptr + 4);
#pragma unroll
        for (int i2 = 0; i2 < 4; ++i2) {
            const float* wp_ = &W1[(size_t)(n0b + i2 * 32 + wn) * 1024 + wk * 8];
            pw[i2][0] = *(const float4*)wp_;
            pw[i2][1] = *(const float4*)(wp_ + 4);
        }
        for (int c = 0; c < 8; ++c) {
            *(f16x8*)&a_s[arow & 31][acol] = cvt8(pa0, pa1);
#pragma unroll
            for (int i2 = 0; i2 < 4; ++i2)
                *(f16x8*)&w_s[((size_t)wk * 128 + i2 * 32 + wn) * 8] =
                    cvt8(pw[i2][0], pw[i2][1]);
            __syncthreads();
            if (c < 7) {
                int cb = (c + 1) * 64;
                pa0 = *(const float4*)(aptr + cb);
                pa1 = *(const float4*)(aptr + cb + 4);
#pragma unroll
                for (int i2 = 0; i2 < 4; ++i2) {
                    const float* wp_ =
                        &W1[(size_t)(n0b + i2 * 32 + wn) * 1024 + cb + wk * 8];
                    pw[i2][0] = *(const float4*)wp_;
                    pw[i2][1] = *(const float4*)(wp_ + 4);
                }
            }
#pragma unroll
            for (int kt = 0; kt < 2; ++kt) {
                f16x8 af = *(const f16x8*)&a_s[m0 + r][kt * 32 + q * 8];
#pragma unroll
                for (int nt = 0; nt < 4; ++nt) {
                    f16x8 bfv = *(const f16x8*)
                        &w_s[((kt * 4 + q) * 128 + n0w + nt * 16 + r) * 8];
                    acc[nt] = __builtin_amdgcn_mfma_f32_16x16x32_f16(
                        af, bfv, acc[nt], 0, 0, 0);
                }
            }
            __syncthreads();
        }
#pragma unroll
        for (int nt = 0; nt < 4; ++nt) {
            int n = n0b + n0w + nt * 16 + r;
            float bv = b1[n];
#pragma unroll
            for (int rr = 0; rr < 4; ++rr)
                labHf[(size_t)(r0 + m0 + 4 * q + rr) * HH + n] =
                    (_Float16)(acc[nt][rr] + bv);
        }
        return;
    }

    // ---- regions 0/2: 64-row x 128-col tile, wave = one 16-row m-tile ----
    const float* Wbase;
    int r0, n0b, wstride, region;
    if (bid < 128) {
        region = 0; Wbase = W1 + 512; wstride = 1024;
        r0 = (bid & 15) * 64; n0b = (bid >> 4) * 128;
    } else {
        region = 2; Wbase = conv_w; wstride = 512;
        r0 = (bid - 152) * 64; n0b = 0;
    }
    const float* aptr0 = &img[(size_t)(r0 + arow) * DD + acol];
    const float* aptr1 = aptr0 + (size_t)32 * DD;
    floatx4 acc[8] = {};
    float4 pa[4], pw[4][2];
    pa[0] = *(const float4*)aptr0;
    pa[1] = *(const float4*)(aptr0 + 4);
    pa[2] = *(const float4*)aptr1;
    pa[3] = *(const float4*)(aptr1 + 4);
#pragma unroll
    for (int i2 = 0; i2 < 4; ++i2) {
        const float* wp_ = &Wbase[(size_t)(n0b + i2 * 32 + wn) * wstride + wk * 8];
        pw[i2][0] = *(const float4*)wp_;
        pw[i2][1] = *(const float4*)(wp_ + 4);
    }
    for (int c = 0; c < 8; ++c) {
        *(f16x8*)&a_s[arow][acol] = cvt8(pa[0], pa[1]);
        *(f16x8*)&a_s[arow + 32][acol] = cvt8(pa[2], pa[3]);
#pragma unroll
        for (int i2 = 0; i2 < 4; ++i2)
            *(f16x8*)&w_s[((size_t)wk * 128 + i2 * 32 + wn) * 8] =
                cvt8(pw[i2][0], pw[i2][1]);
        __syncthreads();
        if (c < 7) {
            int cb = (c + 1) * 64;
            pa[0] = *(const float4*)(aptr0 + cb);
            pa[1] = *(const float4*)(aptr0 + cb + 4);
            pa[2] = *(const float4*)(aptr1 + cb);
            pa[3] = *(const float4*)(aptr1 + cb + 4);
#pragma unroll
            for (int i2 = 0; i2 < 4; ++i2) {
                const float* wp_ =
                    &Wbase[(size_t)(n0b + i2 * 32 + wn) * wstride + cb + wk * 8];
                pw[i2][0] = *(const float4*)wp_;
                pw[i2][1] = *(const float4*)(wp_ + 4);
            }
        }
#pragma unroll
        for (int kt = 0; kt < 2; ++kt) {
            f16x8 af = *(const f16x8*)&a_s[wv * 16 + r][kt * 32 + q * 8];
#pragma unroll
            for (int nt = 0; nt < 8; ++nt) {
                f16x8 bfv = *(const f16x8*)
                    &w_s[((kt * 4 + q) * 128 + nt * 16 + r) * 8];
                acc[nt] = __builtin_amdgcn_mfma_f32_16x16x32_f16(
                    af, bfv, acc[nt], 0, 0, 0);
            }
        }
        __syncthreads();
    }
    if (region == 0) {
#pragma unroll
        for (int nt = 0; nt < 8; ++nt) {
            int n = n0b + nt * 16 + r;
#pragma unroll
            for (int rr = 0; rr < 4; ++rr)
                imgHf[(size_t)(r0 + wv * 16 + 4 * q + rr) * HH + n] =
                    (_Float16)acc[nt][rr];
        }
    } else {
#pragma unroll
        for (int nt = 0; nt < 8; ++nt) {
            int k = nt * 16 + r;
            float bv = conv_b[k];
#pragma unroll
            for (int rr = 0; rr < 4; ++rr) {
                int row = r0 + wv * 16 + 4 * q + rr;
                int b = row >> 9, t = row & 511;
                seg_out[((size_t)b * KK + k) * TT + t] =
                    (acc[nt][rr] + bv) * masks[row];
            }
        }
    }
}

// ---------------- joint (R8 champion): zero-LDS h, reg-staged dbuf W2,
// one barrier/chunk, fp16, exp-tanh, in-register log-softmax.
__global__ __launch_bounds__(256) void joint_kernel6(
    const _Float16* __restrict__ imgHf,  // [B*T][H]
    const _Float16* __restrict__ labHf,  // [B*U][H] (b1 folded)
    const _Float16* __restrict__ W2s,    // swizzled [(h>>3)][k][h&7]
    const float* __restrict__ b2,
    float* __restrict__ out) {           // [B*U*T][K]
    __shared__ __align__(16) _Float16 w_s[2][8192];  // 2 x 16 KB
    int tid = threadIdx.x, bid = blockIdx.x;
    int t0 = (bid & 7) * 64;
    int rest = bid >> 3;
    int u = rest % UU, b = rest / UU;
    int lane = tid & 63, wv = tid >> 6;
    int q = lane >> 4, r = lane & 15;
    const _Float16* imgrow = imgHf + ((size_t)b * TT + t0 + wv * 16 + r) * HH;
    const _Float16* labrow = labHf + (size_t)(b * UU + u) * HH;
    int c0 = q * 8, c1 = 32 + q * 8;
    int ws_off = tid * 8;
    floatx4 acc[8] = {};
    f16x8 ivA = *(const f16x8*)&imgrow[c0];
    f16x8 ivB = *(const f16x8*)&imgrow[c1];
    f16x8 lvA = *(const f16x8*)&labrow[c0];
    f16x8 lvB = *(const f16x8*)&labrow[c1];
    {
        const _Float16* wsrc = W2s;
#pragma unroll
        for (int i2 = 0; i2 < 4; ++i2)
            *(f16x8*)&w_s[0][i2 * 2048 + ws_off] =
                *(const f16x8*)&wsrc[i2 * 2048 + ws_off];
    }
    __syncthreads();
#pragma unroll 2
    for (int c = 0; c < 16; ++c) {
        int buf = c & 1;
        f16x8 nivA, nivB, nlvA, nlvB, nw0, nw1, nw2, nw3;
        if (c < 15) {
            int cb = (c + 1) * 64;
            nivA = *(const f16x8*)&imgrow[cb + c0];
            nivB = *(const f16x8*)&imgrow[cb + c1];
            nlvA = *(const f16x8*)&labrow[cb + c0];
            nlvB = *(const f16x8*)&labrow[cb + c1];
            const _Float16* wsrc = W2s + (size_t)(c + 1) * 8192;
            nw0 = *(const f16x8*)&wsrc[0 * 2048 + ws_off];
            nw1 = *(const f16x8*)&wsrc[1 * 2048 + ws_off];
            nw2 = *(const f16x8*)&wsrc[2 * 2048 + ws_off];
            nw3 = *(const f16x8*)&wsrc[3 * 2048 + ws_off];
        }
        f16x8 a0 = tanh8(ivA + lvA);
        f16x8 a1 = tanh8(ivB + lvB);
#pragma unroll
        for (int nt = 0; nt < 8; ++nt) {
            f16x8 bf0 = *(const f16x8*)&w_s[buf][((0 + q) * 128 + nt * 16 + r) * 8];
            acc[nt] = __builtin_amdgcn_mfma_f32_16x16x32_f16(
                a0, bf0, acc[nt], 0, 0, 0);
        }
#pragma unroll
        for (int nt = 0; nt < 8; ++nt) {
            f16x8 bf1 = *(const f16x8*)&w_s[buf][((4 + q) * 128 + nt * 16 + r) * 8];
            acc[nt] = __builtin_amdgcn_mfma_f32_16x16x32_f16(
                a1, bf1, acc[nt], 0, 0, 0);
        }
        if (c < 15) {
            *(f16x8*)&w_s[buf ^ 1][0 * 2048 + ws_off] = nw0;
            *(f16x8*)&w_s[buf ^ 1][1 * 2048 + ws_off] = nw1;
            *(f16x8*)&w_s[buf ^ 1][2 * 2048 + ws_off] = nw2;
            *(f16x8*)&w_s[buf ^ 1][3 * 2048 + ws_off] = nw3;
            ivA = nivA; ivB = nivB; lvA = nlvA; lvB = nlvB;
        }
        __syncthreads();
    }
    float b2v[8];
#pragma unroll
    for (int nt = 0; nt < 8; ++nt) b2v[nt] = b2[nt * 16 + r];
    float* orow = out + (((size_t)b * UU + u) * TT + t0 + wv * 16) * KK;
#pragma unroll
    for (int rr = 0; rr < 4; ++rr) {
        float v[8];
        float mx = -INFINITY;
#pragma unroll
        for (int nt = 0; nt < 8; ++nt) {
            v[nt] = acc[nt][rr] + b2v[nt];
            mx = fmaxf(mx, v[nt]);
        }
        mx = fmaxf(mx, __shfl_xor(mx, 1, 16));
        mx = fmaxf(mx, __shfl_xor(mx, 2, 16));
        mx = fmaxf(mx, __shfl_xor(mx, 4, 16));
        mx = fmaxf(mx, __shfl_xor(mx, 8, 16));
        float s = 0.f;
#pragma unroll
        for (int nt = 0; nt < 8; ++nt) s += __expf(v[nt] - mx);
        s += __shfl_xor(s, 1, 16);
        s += __shfl_xor(s, 2, 16);
        s += __shfl_xor(s, 4, 16);
        s += __shfl_xor(s, 8, 16);
        float lse = mx + __logf(s);
        int row = 4 * q + rr;
#pragma unroll
        for (int nt = 0; nt < 8; ++nt)
            orow[(size_t)row * KK + nt * 16 + r] = v[nt] - lse;
    }
}

extern "C" void kernel_launch(void* const* d_in, const int* in_sizes, int n_in,
                              void* d_out, int out_size, void* d_ws, size_t ws_size,
                              hipStream_t stream) {
    const float* img    = (const float*)d_in[0];
    const float* labf   = (const float*)d_in[1];
    const float* masks  = (const float*)d_in[2];
    const float* W1     = (const float*)d_in[3];
    const float* b1     = (const float*)d_in[4];
    const float* W2     = (const float*)d_in[5];
    const float* b2     = (const float*)d_in[6];
    const float* conv_w = (const float*)d_in[7];
    const float* conv_b = (const float*)d_in[8];
    float* out = (float*)d_out;

    _Float16* base  = (_Float16*)d_ws;
    _Float16* imgHf = base;                    // [1024][1024]
    _Float16* labHf = imgHf + 1024 * 1024;     // [96][1024]
    _Float16* W2s   = labHf + 96 * 1024;       // [H/8][K][8] = 131072

    mid_kernel5<<<184, 256, 0, stream>>>(img, labf, W1, W2, conv_w,
                                         b1, conv_b, masks,
                                         imgHf, labHf, W2s, out);
    joint_kernel6<<<768, 256, 0, stream>>>(imgHf, labHf, W2s, b2,
                                           out + (size_t)BB * KK * TT);
}